// Round 6
// baseline (1035.822 us; speedup 1.0000x reference)
//
#include <hip/hip_runtime.h>

typedef __bf16 bf16x8 __attribute__((ext_vector_type(8)));
typedef float f32x4 __attribute__((ext_vector_type(4)));
typedef int i32x4 __attribute__((ext_vector_type(4)));

#define MFMA(a, b, c) __builtin_amdgcn_mfma_f32_16x16x32_bf16((a), (b), (c), 0, 0, 0)

constexpr int HEADS = 8, SEQ = 4096, FIN = 512, HD = 64, FOUT = 512;
// 1/sqrt(64) * log2(e): fold softmax scale + exp->exp2 conversion into Q
constexpr float QSCALE = 0.18033688011112042f;

// Load 8 contiguous fp32, convert to a bf16x8 MFMA fragment (ptr must be 16B-aligned).
__device__ inline bf16x8 cvt8(const float* __restrict__ p) {
    f32x4 a = *(const f32x4*)p;
    f32x4 b = *(const f32x4*)(p + 4);
    bf16x8 r;
    r[0] = (__bf16)a[0]; r[1] = (__bf16)a[1]; r[2] = (__bf16)a[2]; r[3] = (__bf16)a[3];
    r[4] = (__bf16)b[0]; r[5] = (__bf16)b[1]; r[6] = (__bf16)b[2]; r[7] = (__bf16)b[3];
    return r;
}

// ---------------- Kernel 1: QKV projection (fp32 in -> bf16 ws) ----------------
__global__ __launch_bounds__(256) void qkv_kernel(
    const float* __restrict__ X, const float* __restrict__ Wq,
    const float* __restrict__ Wk, const float* __restrict__ Wv,
    __bf16* __restrict__ Q, __bf16* __restrict__ K, __bf16* __restrict__ Vt)
{
    const int h = blockIdx.y;
    const int tid = threadIdx.x;
    const int w = tid >> 6, lane = tid & 63;
    const int quad = lane >> 4, l16 = lane & 15;
    const int m = blockIdx.x * 64 + w * 16 + l16;

    const float* xrow = X + ((size_t)h * SEQ + m) * FIN + quad * 8;
    const float* wqh = Wq + (size_t)h * HD * FIN + quad * 8;
    const float* wkh = Wk + (size_t)h * HD * FIN + quad * 8;
    const float* wvh = Wv + (size_t)h * HD * FIN + quad * 8;

    const f32x4 vzero = {0.f, 0.f, 0.f, 0.f};
    f32x4 accQ[4], accK[4], accV[4];
#pragma unroll
    for (int t = 0; t < 4; ++t) { accQ[t] = vzero; accK[t] = vzero; accV[t] = vzero; }

    for (int f0 = 0; f0 < FIN; f0 += 32) {
        bf16x8 a = cvt8(xrow + f0);
#pragma unroll
        for (int t = 0; t < 4; ++t) {
            const int wrow = (t * 16 + l16) * FIN + f0;
            bf16x8 bq = cvt8(wqh + wrow);
            bf16x8 bk = cvt8(wkh + wrow);
            bf16x8 bv = cvt8(wvh + wrow);
            accQ[t] = MFMA(a, bq, accQ[t]);
            accK[t] = MFMA(a, bk, accK[t]);
            accV[t] = MFMA(a, bv, accV[t]);
        }
    }

    const int row0 = blockIdx.x * 64 + w * 16 + quad * 4;
#pragma unroll
    for (int t = 0; t < 4; ++t) {
        const int d = t * 16 + l16;
#pragma unroll
        for (int r = 0; r < 4; ++r) {
            const int n = row0 + r;
            Q[((size_t)h * SEQ + n) * HD + d] = (__bf16)(accQ[t][r] * QSCALE);
            K[((size_t)h * SEQ + n) * HD + d] = (__bf16)accK[t][r];
            Vt[((size_t)h * HD + d) * SEQ + n] = (__bf16)accV[t][r];
        }
    }
}

// ---------------- Kernel 2: masked flash attention, S^T, NO K/V STAGING ------
// Round-5 measurement: removing attn's 537MB mask stream changed attn by ~0 ->
// attn is NOT memory-bound; the stalls are structural. The remaining structural
// cost is the per-tile vmcnt(0)+s_barrier convoy protecting the K/V LDS dbuf.
// K/V per head = 1MB, L2/XCD = 4MB: it L2-fits. Per catalog common-mistake #7
// (m169: dropping LDS staging of L2-fit data = +26%), this version reads K/V
// fragments DIRECTLY from global into MFMA operands:
//   * no stage(), no double-buffer, and NO __syncthreads anywhere in the loop
//     (the barrier only protected the dbuf; PT is per-wave-private LDS)
//   * 8 independent wave streams/CU, every load hidden by other waves' compute
//   * K loads: contiguous 2KB/instr; V loads: 16 fully-used 64B lines/instr
//   * tile math, mask ping-pong (r3-verified), PT swizzle, epilogue unchanged
// LDS: PT only, 4 waves x 2KB = 8KB.
__global__ __launch_bounds__(256) void attn_kernel(
    const __bf16* __restrict__ Q, const __bf16* __restrict__ K,
    const __bf16* __restrict__ Vt, const int* __restrict__ mask,
    __bf16* __restrict__ Hcat)
{
    __shared__ __align__(16) __bf16 PT_lds[4 * 1024];   // per-wave 16x64 P tile

    const int bid = blockIdx.x;
    const int h = bid & 7;           // XCD-pinned head (round-robin dispatch heuristic)
    const int q0b = (bid >> 3) * 64;
    const int tid = threadIdx.x;
    const int w = tid >> 6, lane = tid & 63;
    const int quad = lane >> 4, l16 = lane & 15;
    const int q0 = q0b + w * 16;
    const int e7 = l16 & 7;          // XOR-swizzle key for this lane's PT rows

    __bf16* PT = PT_lds + w * 1024;  // 16 q-rows x 64 keys, chunk-swizzled

    const __bf16* Qh = Q + (size_t)h * SEQ * HD;
    const __bf16* Kh = K + (size_t)h * SEQ * HD;
    const __bf16* Vh = Vt + (size_t)h * HD * SEQ;
    const int* mrow = mask + ((size_t)h * SEQ + q0 + l16) * SEQ + quad * 4;

    // mask for tile n0 -> 4 register i32x4 (lane's 16 key-columns) [r3-verified]
    auto loadM = [&](int n0, i32x4* mv) {
#pragma unroll
        for (int t = 0; t < 4; ++t) mv[t] = *(const i32x4*)(mrow + n0 + t * 16);
    };

    // Q fragments (B operand) held in registers for the whole key loop
    bf16x8 qa0 = *(const bf16x8*)(Qh + (size_t)(q0 + l16) * HD + quad * 8);
    bf16x8 qa1 = *(const bf16x8*)(Qh + (size_t)(q0 + l16) * HD + 32 + quad * 8);

    const f32x4 vzero = {0.f, 0.f, 0.f, 0.f};
    f32x4 O[4];
    float ls0 = 0.f, ls1 = 0.f, ls2 = 0.f, ls3 = 0.f;
#pragma unroll
    for (int t = 0; t < 4; ++t) O[t] = vzero;

    i32x4 mA[4], mB[4];
    loadM(0, mA);

    auto tile = [&](int i, const i32x4* mc, i32x4* mn) {
        const int n0 = i * 64;
        if (i + 1 < SEQ / 64) loadM(n0 + 64, mn);   // mask prefetch (ping-pong)

        // ---- S^T = K . Q^T : K fragments straight from global (L2-resident)
        // lane owns q = q0+l16, keys = n0+t*16+quad*4+{0..3}
        f32x4 St[4];
        __builtin_amdgcn_s_setprio(1);
#pragma unroll
        for (int t = 0; t < 4; ++t) {
            const __bf16* krow = Kh + (size_t)(n0 + t * 16 + l16) * HD;
            bf16x8 kb0 = *(const bf16x8*)(krow + quad * 8);        // hd 0..31
            bf16x8 kb1 = *(const bf16x8*)(krow + 32 + quad * 8);   // hd 32..63
            St[t] = MFMA(kb0, qa0, vzero);   // A = K rows, B = Q rows -> S^T
            St[t] = MFMA(kb1, qa1, St[t]);
        }
        __builtin_amdgcn_s_setprio(0);

        // ---- p = mask ? exp2(s) : 0 ; pack 4 keys -> one ds_write_b64 ----
        // PT chunk-swizzle: key chunk c of row l16 lives at element ((c^e7)*8)
#pragma unroll
        for (int t = 0; t < 4; ++t) {
            union { unsigned long long u; __bf16 hh[4]; } pk;
            float psub0 = 0.f, psub1 = 0.f;
#pragma unroll
            for (int r = 0; r < 4; ++r) {
                float p = __builtin_amdgcn_exp2f(St[t][r]);
                p = mc[t][r] ? p : 0.f;
                if (r & 1) psub1 += p; else psub0 += p;
                pk.hh[r] = (__bf16)p;
            }
            // 4 independent accumulators: no 16-deep serial add chain
            if (t == 0) ls0 += psub0 + psub1;
            else if (t == 1) ls1 += psub0 + psub1;
            else if (t == 2) ls2 += psub0 + psub1;
            else ls3 += psub0 + psub1;
            const int c = t * 2 + (quad >> 1);   // 8-el chunk holding keys t*16+quad*4..+3
            *(unsigned long long*)(PT + l16 * 64 + ((c ^ e7) * 8) + (quad & 1) * 4) = pk.u;
        }

        // ---- O += P . V  (P from swizzled PT; V straight from global) ----
        bf16x8 pa0 = *(const bf16x8*)(PT + l16 * 64 + ((quad ^ e7) * 8));
        bf16x8 pa1 = *(const bf16x8*)(PT + l16 * 64 + (((quad + 4) ^ e7) * 8));
        __builtin_amdgcn_s_setprio(1);
#pragma unroll
        for (int t = 0; t < 4; ++t) {
            const __bf16* vrow = Vh + (size_t)(t * 16 + l16) * SEQ + n0;
            bf16x8 vb0 = *(const bf16x8*)(vrow + quad * 8);        // keys n0+0..31
            bf16x8 vb1 = *(const bf16x8*)(vrow + 32 + quad * 8);   // keys n0+32..63
            O[t] = MFMA(pa0, vb0, O[t]);
            O[t] = MFMA(pa1, vb1, O[t]);
        }
        __builtin_amdgcn_s_setprio(0);
        // no barrier: PT is per-wave private; same-wave DS ordering protects reuse
    };

    for (int i = 0; i < SEQ / 64; i += 2) {   // ping-pong mask regs, no copies
        tile(i, mA, mB);
        tile(i + 1, mB, mA);
    }

    // ---- l: reduce over the 4 quads holding q=l16, then transpose to C rows ----
    float lsum = (ls0 + ls1) + (ls2 + ls3);
    lsum += __shfl_xor(lsum, 16, 64);
    lsum += __shfl_xor(lsum, 32, 64);   // L[l16], uniform across quads
    float inv[4];
#pragma unroll
    for (int r = 0; r < 4; ++r) {
        float Lr = __shfl(lsum, quad * 4 + r, 64);
        inv[r] = Lr > 0.f ? 1.0f / Lr : 0.f;
    }

    // ---- epilogue: Hcat[n, h*64 + d] = O / l ----
#pragma unroll
    for (int r = 0; r < 4; ++r) {
        const int n = q0 + quad * 4 + r;
#pragma unroll
        for (int t = 0; t < 4; ++t)
            Hcat[(size_t)n * FOUT + h * HD + t * 16 + l16] = (__bf16)(O[t][r] * inv[r]);
    }
}

// ---------------- Kernel 3: output projection ----------------
__global__ __launch_bounds__(256) void out_kernel(
    const __bf16* __restrict__ Hcat, const float* __restrict__ Wo,
    float* __restrict__ out)
{
    const int tid = threadIdx.x;
    const int w = tid >> 6, lane = tid & 63;
    const int quad = lane >> 4, l16 = lane & 15;
    const int n0 = blockIdx.x * 64 + w * 16;
    const int o0 = blockIdx.y * 64;

    const f32x4 vzero = {0.f, 0.f, 0.f, 0.f};
    f32x4 acc[4];
#pragma unroll
    for (int t = 0; t < 4; ++t) acc[t] = vzero;

    for (int k0 = 0; k0 < FOUT; k0 += 32) {
        bf16x8 a = *(const bf16x8*)(Hcat + (size_t)(n0 + l16) * FOUT + k0 + quad * 8);
#pragma unroll
        for (int t = 0; t < 4; ++t) {
            bf16x8 b = cvt8(Wo + (size_t)(o0 + t * 16 + l16) * FOUT + k0 + quad * 8);
            acc[t] = MFMA(a, b, acc[t]);
        }
    }
#pragma unroll
    for (int t = 0; t < 4; ++t)
#pragma unroll
        for (int r = 0; r < 4; ++r)
            out[(size_t)(n0 + quad * 4 + r) * FOUT + o0 + t * 16 + l16] = acc[t][r];
}

extern "C" void kernel_launch(void* const* d_in, const int* in_sizes, int n_in,
                              void* d_out, int out_size, void* d_ws, size_t ws_size,
                              hipStream_t stream) {
    const float* X    = (const float*)d_in[0];
    const int*   mask = (const int*)d_in[1];
    const float* Wq   = (const float*)d_in[2];
    const float* Wk   = (const float*)d_in[3];
    const float* Wv   = (const float*)d_in[4];
    const float* Wo   = (const float*)d_in[5];
    float* out = (float*)d_out;

    __bf16* Q    = (__bf16*)d_ws;
    __bf16* K    = Q + (size_t)HEADS * SEQ * HD;
    __bf16* Vt   = K + (size_t)HEADS * SEQ * HD;
    __bf16* Hcat = Vt + (size_t)HEADS * HD * SEQ;

    qkv_kernel<<<dim3(SEQ / 64, HEADS), 256, 0, stream>>>(X, Wq, Wk, Wv, Q, K, Vt);
    attn_kernel<<<(SEQ / 64) * HEADS, 256, 0, stream>>>(Q, K, Vt, mask, Hcat);
    out_kernel<<<dim3(SEQ / 64, FOUT / 64), 256, 0, stream>>>(Hcat, Wo, out);
}

// Round 7
// 914.251 us; speedup vs baseline: 1.1330x; 1.1330x over previous
//
#include <hip/hip_runtime.h>

typedef __bf16 bf16x8 __attribute__((ext_vector_type(8)));
typedef float f32x4 __attribute__((ext_vector_type(4)));
typedef int i32x4 __attribute__((ext_vector_type(4)));

#define MFMA(a, b, c) __builtin_amdgcn_mfma_f32_16x16x32_bf16((a), (b), (c), 0, 0, 0)
#define GLOAD_LDS(g, l) __builtin_amdgcn_global_load_lds( \
    (const __attribute__((address_space(1))) void*)(g),   \
    (__attribute__((address_space(3))) void*)(l), 16, 0, 0)

constexpr int HEADS = 8, SEQ = 4096, FIN = 512, HD = 64, FOUT = 512;
// 1/sqrt(64) * log2(e): fold softmax scale + exp->exp2 conversion into Q
constexpr float QSCALE = 0.18033688011112042f;

// Load 8 contiguous fp32, convert to a bf16x8 MFMA fragment (ptr must be 16B-aligned).
__device__ inline bf16x8 cvt8(const float* __restrict__ p) {
    f32x4 a = *(const f32x4*)p;
    f32x4 b = *(const f32x4*)(p + 4);
    bf16x8 r;
    r[0] = (__bf16)a[0]; r[1] = (__bf16)a[1]; r[2] = (__bf16)a[2]; r[3] = (__bf16)a[3];
    r[4] = (__bf16)b[0]; r[5] = (__bf16)b[1]; r[6] = (__bf16)b[2]; r[7] = (__bf16)b[3];
    return r;
}

// ---------------- Kernel 1: QKV projection (fp32 in -> bf16 ws) ----------------
__global__ __launch_bounds__(256) void qkv_kernel(
    const float* __restrict__ X, const float* __restrict__ Wq,
    const float* __restrict__ Wk, const float* __restrict__ Wv,
    __bf16* __restrict__ Q, __bf16* __restrict__ K, __bf16* __restrict__ Vt)
{
    const int h = blockIdx.y;
    const int tid = threadIdx.x;
    const int w = tid >> 6, lane = tid & 63;
    const int quad = lane >> 4, l16 = lane & 15;
    const int m = blockIdx.x * 64 + w * 16 + l16;

    const float* xrow = X + ((size_t)h * SEQ + m) * FIN + quad * 8;
    const float* wqh = Wq + (size_t)h * HD * FIN + quad * 8;
    const float* wkh = Wk + (size_t)h * HD * FIN + quad * 8;
    const float* wvh = Wv + (size_t)h * HD * FIN + quad * 8;

    const f32x4 vzero = {0.f, 0.f, 0.f, 0.f};
    f32x4 accQ[4], accK[4], accV[4];
#pragma unroll
    for (int t = 0; t < 4; ++t) { accQ[t] = vzero; accK[t] = vzero; accV[t] = vzero; }

    for (int f0 = 0; f0 < FIN; f0 += 32) {
        bf16x8 a = cvt8(xrow + f0);
#pragma unroll
        for (int t = 0; t < 4; ++t) {
            const int wrow = (t * 16 + l16) * FIN + f0;
            bf16x8 bq = cvt8(wqh + wrow);
            bf16x8 bk = cvt8(wkh + wrow);
            bf16x8 bv = cvt8(wvh + wrow);
            accQ[t] = MFMA(a, bq, accQ[t]);
            accK[t] = MFMA(a, bk, accK[t]);
            accV[t] = MFMA(a, bv, accV[t]);
        }
    }

    const int row0 = blockIdx.x * 64 + w * 16 + quad * 4;
#pragma unroll
    for (int t = 0; t < 4; ++t) {
        const int d = t * 16 + l16;
#pragma unroll
        for (int r = 0; r < 4; ++r) {
            const int n = row0 + r;
            Q[((size_t)h * SEQ + n) * HD + d] = (__bf16)(accQ[t][r] * QSCALE);
            K[((size_t)h * SEQ + n) * HD + d] = (__bf16)accK[t][r];
            Vt[((size_t)h * HD + d) * SEQ + n] = (__bf16)accV[t][r];
        }
    }
}

// ---------------- Kernel 2: masked flash attention, KEY-SPLIT waves ----------
// Probe history: r1 occupancy null, r5 memory null, r6 staging-removal -146us
// -> LDS read bandwidth is the limiter. Old layout: every wave read the FULL
// 8KB K + 8KB V tile (+4KB PT round-trip) = ~160KB LDS reads per CU-tile.
// New: wave w owns keys [w*16, w*16+16) x ALL 64 q of the block.
//   * K frags: 2 ds_read_b128/wave/tile (only its 16 K rows; was 8)
//   * V frags: 4 ds_read_b64/wave/tile (was 8 b128)
//   * PT round-trip ELIMINATED: S^T=K.Q^T C-layout (col=lane&15=q,
//     row=quad*4+r=key) IS the PV A-frag layout (row=lane&15=q,
//     k-slot=quad*8+j) -> softmax feeds PV in-lane, zero shuffles.
//     PV uses 16x16x32 with upper 4 k-slots zeroed on A and B.
//   * per-CU LDS reads/tile: ~160KB -> ~32KB (5x)
// Waves hold key-partial O/lsum -> tail cross-wave reduce via LDS (aliased
// over the dead dbuf, stride-68 pad, 2 barriers, once per block).
// SYNC SKELETON IDENTICAL TO r3-verified: same stage(), same dbuf, same one
// barrier per tile, mask ping-pong in regs.
// LDS: loop: K dbuf [0,16K) | V dbuf [16K,32K). tail: Ored 4x[64][68]f32 + Lred.
__global__ __launch_bounds__(256) void attn_kernel(
    const __bf16* __restrict__ Q, const __bf16* __restrict__ K,
    const __bf16* __restrict__ Vt, const int* __restrict__ mask,
    __bf16* __restrict__ Hcat)
{
    __shared__ __align__(16) unsigned char lds[4 * 64 * 68 * 4 + 4 * 64 * 4]; // 70656B

    const int bid = blockIdx.x;
    const int h = bid & 7;           // XCD-pinned head (round-robin dispatch heuristic)
    const int q0b = (bid >> 3) * 64;
    const int tid = threadIdx.x;
    const int w = tid >> 6, lane = tid & 63;
    const int quad = lane >> 4, l16 = lane & 15;
    const int e7 = l16 & 7;          // XOR-swizzle key for this lane's rows

    const __bf16* Qh = Q + (size_t)h * SEQ * HD;
    const __bf16* Kh = K + (size_t)h * SEQ * HD;
    const __bf16* Vh = Vt + (size_t)h * HD * SEQ;
    // lane (g-loop) reads mask[q0b + g*16 + l16][n0 + w*16 + quad*4 + {0..3}]
    const int* mbase = mask + ((size_t)h * SEQ + q0b + l16) * SEQ + w * 16 + quad * 4;

    // stage: BYTE-IDENTICAL to r3-verified (XOR chunk swizzle, dbuf b)
    auto stage = [&](int n0, int b) {
        unsigned char* bK = lds + b * 8192;
        unsigned char* bV = lds + 16384 + b * 8192;
#pragma unroll
        for (int c = 0; c < 2; ++c) {
            const int s = c * 256 + w * 64 + lane;   // 0..511
            const int row = s >> 3;
            const int cq = (s & 7) ^ (row & 7);
            GLOAD_LDS(Kh + (size_t)(n0 + row) * HD + cq * 8, bK + (c * 256 + w * 64) * 16);
            GLOAD_LDS(Vh + (size_t)row * SEQ + n0 + cq * 8, bV + (c * 256 + w * 64) * 16);
        }
    };
    // mask for tile n0 -> 4 register i32x4 (one per q-group g)
    auto loadM = [&](int n0, i32x4* mv) {
#pragma unroll
        for (int g = 0; g < 4; ++g) mv[g] = *(const i32x4*)(mbase + g * (16 * SEQ) + n0);
    };

    // Q fragments (B operand), all 64 q-rows of the block: qa[g][c]
    bf16x8 qa[4][2];
#pragma unroll
    for (int g = 0; g < 4; ++g)
#pragma unroll
        for (int c = 0; c < 2; ++c)
            qa[g][c] = *(const bf16x8*)(Qh + (size_t)(q0b + g * 16 + l16) * HD + c * 32 + quad * 8);

    const f32x4 vzero = {0.f, 0.f, 0.f, 0.f};
    f32x4 O[4][4];                   // O[g][u]: q=g*16+quad*4+r, hd=u*16+l16 (key-partial)
    float ls[4] = {0.f, 0.f, 0.f, 0.f};
#pragma unroll
    for (int g = 0; g < 4; ++g)
#pragma unroll
        for (int u = 0; u < 4; ++u) O[g][u] = vzero;

    i32x4 mA[4], mB[4];
    stage(0, 0);
    loadM(0, mA);
    __syncthreads();

    auto tile = [&](int i, const i32x4* mc, i32x4* mn) {
        const int n0 = i * 64;
        const int cur = i & 1;
        if (i + 1 < SEQ / 64) {      // prefetch next tile (K/V -> LDS, mask -> regs)
            stage(n0 + 64, cur ^ 1);
            loadM(n0 + 64, mn);
        }
        const __bf16* cK = (const __bf16*)(lds + cur * 8192);
        const __bf16* cV = (const __bf16*)(lds + 16384 + cur * 8192);

        // ---- K frags: wave's OWN 16 rows only (2 reads; same swizzle form as r3)
        const int krow = w * 16 + l16;
        bf16x8 kb0 = *(const bf16x8*)(cK + krow * 64 + ((quad ^ e7) * 8));
        bf16x8 kb1 = *(const bf16x8*)(cK + krow * 64 + (((quad + 4) ^ e7) * 8));

        // ---- S^T = K . Q^T : lane holds q = g*16+l16 (col), key = w*16+quad*4+r
        f32x4 St[4];
        __builtin_amdgcn_s_setprio(1);
#pragma unroll
        for (int g = 0; g < 4; ++g) {
            St[g] = MFMA(kb0, qa[g][0], vzero);
            St[g] = MFMA(kb1, qa[g][1], St[g]);
        }
        __builtin_amdgcn_s_setprio(0);

        // ---- p = mask ? exp2(s) : 0 -> PV A-frags IN-LANE (k-slots quad*8+r,
        // upper 4 slots zero; matching B zero-pad makes them dead)
        bf16x8 pa[4];
#pragma unroll
        for (int g = 0; g < 4; ++g) {
            bf16x8 z = {};
#pragma unroll
            for (int r = 0; r < 4; ++r) {
                float p = __builtin_amdgcn_exp2f(St[g][r]);
                p = mc[g][r] ? p : 0.f;
                ls[g] += p;
                z[r] = (__bf16)p;
            }
            pa[g] = z;
        }

        // ---- O += P . V : vb = V[u*16+l16][keys w*16+quad*4+{0..3}] (b64 + zeros)
        __builtin_amdgcn_s_setprio(1);
        const int vslot = (w * 2 + (quad >> 1)) ^ e7;
        const int vsub = (quad & 1) * 4;
#pragma unroll
        for (int u = 0; u < 4; ++u) {
            bf16x8 vb = {};
            *(unsigned long long*)&vb =
                *(const unsigned long long*)(cV + (u * 16 + l16) * 64 + vslot * 8 + vsub);
#pragma unroll
            for (int g = 0; g < 4; ++g)
                O[g][u] = MFMA(pa[g], vb, O[g][u]);
        }
        __builtin_amdgcn_s_setprio(0);
        __syncthreads();  // drain prefetch + protect buffer reuse (single barrier)
    };

    for (int i = 0; i < SEQ / 64; i += 2) {   // ping-pong mask regs, no copies
        tile(i, mA, mB);
        tile(i + 1, mB, mA);
    }

    // ---- tail: cross-wave (key-split) reduction via LDS, aliased over dbuf ----
    // Loop's final barrier guarantees all dbuf reads/DMA are done.
    float* Ored = (float*)lds;                         // [4][64][68] (pad: no conflicts)
    float* Lred = (float*)(lds + 4 * 64 * 68 * 4);     // [4][64]
    float* myO = Ored + w * (64 * 68);
#pragma unroll
    for (int g = 0; g < 4; ++g) {
#pragma unroll
        for (int u = 0; u < 4; ++u)
#pragma unroll
            for (int r = 0; r < 4; ++r)
                myO[(g * 16 + quad * 4 + r) * 68 + u * 16 + l16] = O[g][u][r];
        float s = ls[g];
        s += __shfl_xor(s, 16, 64);
        s += __shfl_xor(s, 32, 64);           // sum over quads: total for q=g*16+l16
        if (lane < 16) Lred[w * 64 + g * 16 + lane] = s;
    }
    __syncthreads();

    // combine 4 key-partials, normalize, store. thread: q = tid>>2, d0 = (tid&3)*16
    const int q = tid >> 2, d0 = (tid & 3) * 16;
    const float l = Lred[q] + Lred[64 + q] + Lred[128 + q] + Lred[192 + q];
    const float inv = l > 0.f ? 1.0f / l : 0.f;
    float acc[16];
#pragma unroll
    for (int v = 0; v < 4; ++v) {
        f32x4 s = *(const f32x4*)(Ored + q * 68 + d0 + v * 4);
#pragma unroll
        for (int w2 = 1; w2 < 4; ++w2)
            s += *(const f32x4*)(Ored + w2 * (64 * 68) + q * 68 + d0 + v * 4);
#pragma unroll
        for (int j = 0; j < 4; ++j) acc[v * 4 + j] = s[j];
    }
    bf16x8 o0, o1;
#pragma unroll
    for (int j = 0; j < 8; ++j) {
        o0[j] = (__bf16)(acc[j] * inv);
        o1[j] = (__bf16)(acc[8 + j] * inv);
    }
    __bf16* dst = Hcat + (size_t)(q0b + q) * FOUT + h * HD + d0;
    *(bf16x8*)dst = o0;
    *(bf16x8*)(dst + 8) = o1;
}

// ---------------- Kernel 3: output projection ----------------
__global__ __launch_bounds__(256) void out_kernel(
    const __bf16* __restrict__ Hcat, const float* __restrict__ Wo,
    float* __restrict__ out)
{
    const int tid = threadIdx.x;
    const int w = tid >> 6, lane = tid & 63;
    const int quad = lane >> 4, l16 = lane & 15;
    const int n0 = blockIdx.x * 64 + w * 16;
    const int o0 = blockIdx.y * 64;

    const f32x4 vzero = {0.f, 0.f, 0.f, 0.f};
    f32x4 acc[4];
#pragma unroll
    for (int t = 0; t < 4; ++t) acc[t] = vzero;

    for (int k0 = 0; k0 < FOUT; k0 += 32) {
        bf16x8 a = *(const bf16x8*)(Hcat + (size_t)(n0 + l16) * FOUT + k0 + quad * 8);
#pragma unroll
        for (int t = 0; t < 4; ++t) {
            bf16x8 b = cvt8(Wo + (size_t)(o0 + t * 16 + l16) * FOUT + k0 + quad * 8);
            acc[t] = MFMA(a, b, acc[t]);
        }
    }
#pragma unroll
    for (int t = 0; t < 4; ++t)
#pragma unroll
        for (int r = 0; r < 4; ++r)
            out[(size_t)(n0 + quad * 4 + r) * FOUT + o0 + t * 16 + l16] = acc[t][r];
}

extern "C" void kernel_launch(void* const* d_in, const int* in_sizes, int n_in,
                              void* d_out, int out_size, void* d_ws, size_t ws_size,
                              hipStream_t stream) {
    const float* X    = (const float*)d_in[0];
    const int*   mask = (const int*)d_in[1];
    const float* Wq   = (const float*)d_in[2];
    const float* Wk   = (const float*)d_in[3];
    const float* Wv   = (const float*)d_in[4];
    const float* Wo   = (const float*)d_in[5];
    float* out = (float*)d_out;

    __bf16* Q    = (__bf16*)d_ws;
    __bf16* K    = Q + (size_t)HEADS * SEQ * HD;
    __bf16* Vt   = K + (size_t)HEADS * SEQ * HD;
    __bf16* Hcat = Vt + (size_t)HEADS * HD * SEQ;

    qkv_kernel<<<dim3(SEQ / 64, HEADS), 256, 0, stream>>>(X, Wq, Wk, Wv, Q, K, Vt);
    attn_kernel<<<(SEQ / 64) * HEADS, 256, 0, stream>>>(Q, K, Vt, mask, Hcat);
    out_kernel<<<dim3(SEQ / 64, FOUT / 64), 256, 0, stream>>>(Hcat, Wo, out);
}